// Round 4
// baseline (984.041 us; speedup 1.0000x reference)
//
#include <hip/hip_runtime.h>
#include <math.h>

#define LRES 8192
#define TOPK 30

typedef _Float16 half8 __attribute__((ext_vector_type(8)));
typedef float f32x4 __attribute__((ext_vector_type(4)));

// EDGES[:,0] (atom at residue i) and EDGES[:,1] (atom at neighbor j)
__device__ __constant__ int c_ea[25] = {1,0,2,3,4,1,1,1,1,0,0,0,4,4,3,0,2,3,4,2,3,4,2,3,2};
__device__ __constant__ int c_eb[25] = {1,0,2,3,4,0,2,3,4,2,3,4,2,3,2,1,1,1,1,0,0,0,4,4,3};

// ---------------------------------------------------------------- prep: Y5 + packed Ca
__global__ __launch_bounds__(256) void prep_kernel(const float* __restrict__ X,
                                                   float* __restrict__ Y5,
                                                   float* __restrict__ CaP) {
    int i = blockIdx.x * 256 + threadIdx.x;
    const float* x = X + i * 12;
    float N0 = x[0], N1 = x[1], N2 = x[2];
    float A0 = x[3], A1 = x[4], A2 = x[5];   // Ca
    float C0 = x[6], C1 = x[7], C2 = x[8];
    float O0 = x[9], O1 = x[10], O2 = x[11];
    float bx = A0 - N0, by = A1 - N1, bz = A2 - N2;
    float cx = C0 - A0, cy = C1 - A1, cz = C2 - A2;
    float rx = by * cz - bz * cy;
    float ry = bz * cx - bx * cz;
    float rz = bx * cy - by * cx;
    float Bx = -0.58273431f * rx + 0.56802827f * bx - 0.54067466f * cx + A0;
    float By = -0.58273431f * ry + 0.56802827f * by - 0.54067466f * cy + A1;
    float Bz = -0.58273431f * rz + 0.56802827f * bz - 0.54067466f * cz + A2;
    float* y = Y5 + i * 15;
    y[0] = N0; y[1] = N1; y[2] = N2;
    y[3] = A0; y[4] = A1; y[5] = A2;
    y[6] = C0; y[7] = C1; y[8] = C2;
    y[9] = O0; y[10] = O1; y[11] = O2;
    y[12] = Bx; y[13] = By; y[14] = Bz;
    CaP[i * 3 + 0] = A0; CaP[i * 3 + 1] = A1; CaP[i * 3 + 2] = A2;
}

// ------------------------------------------- positional table T[66][128] = (pe_w[d]+pe_b) @ W[0:16]
__global__ __launch_bounds__(256) void pet_kernel(const float* __restrict__ pe_w,
                                                  const float* __restrict__ pe_b,
                                                  const float* __restrict__ edge_w,
                                                  float* __restrict__ T) {
    int idx = blockIdx.x * 256 + threadIdx.x;
    if (idx >= 66 * 128) return;
    int d = idx >> 7, c = idx & 127;
    float acc = 0.f;
    #pragma unroll
    for (int r = 0; r < 16; ++r)
        acc += (pe_w[d * 16 + r] + pe_b[r]) * edge_w[r * 128 + c];
    T[idx] = acc;
}

// ------------------------------------------- W2 -> fp16 col-major [128][424], K padded 400->424 w/ 0
__global__ __launch_bounds__(256) void wcvt_kernel(const float* __restrict__ edge_w,
                                                   _Float16* __restrict__ Wt) {
    int idx = blockIdx.x * 256 + threadIdx.x;
    if (idx >= 128 * 424) return;
    int c = idx / 424, k = idx - c * 424;
    Wt[idx] = (k < 400) ? (_Float16)edge_w[(16 + k) * 128 + c] : (_Float16)0.0f;
}

// ---------------------------------------------------------------- exact top-30 per row: radix select
__device__ __forceinline__ unsigned long long dist_key(const float* __restrict__ CaP, int j,
                                                       double cax, double cay, double caz) {
    double dx = (double)CaP[j * 3 + 0] - cax;
    double dy = (double)CaP[j * 3 + 1] - cay;
    double dz = (double)CaP[j * 3 + 2] - caz;
    double s = dx * dx + dy * dy + dz * dz;   // >=0: bit pattern order-monotone
    return (unsigned long long)__double_as_longlong(s);
}

__global__ __launch_bounds__(256, 4) void topk_kernel(const float* __restrict__ CaP,
                                                      const float* __restrict__ mask,
                                                      int* __restrict__ eidx,
                                                      float* __restrict__ eidx_f) {
    int row = blockIdx.x;
    int tid = threadIdx.x;
    __shared__ unsigned int sHist[256];
    __shared__ unsigned int sPrefix, sRem, sCnt;
    __shared__ unsigned long long sCandKey[64];
    __shared__ int sCandIdx[64];

    double cax = (double)CaP[row * 3 + 0];
    double cay = (double)CaP[row * 3 + 1];
    double caz = (double)CaP[row * 3 + 2];
    float mi = mask[row];

    // per-thread keys: hi-32 of f64 dist^2 (u32, register-resident)
    unsigned int khi[32];
    #pragma unroll
    for (int t = 0; t < 32; ++t) {
        int j = tid + (t << 8);
        unsigned long long kb = dist_key(CaP, j, cax, cay, caz);
        unsigned int h = (unsigned int)(kb >> 32);
        if (mi * mask[j] == 0.0f) h = 0xFFFFFFFFu;
        khi[t] = h;
    }
    if (tid == 0) { sPrefix = 0u; sRem = TOPK - 1; sCnt = 0u; }

    // 4 radix passes, 8 bits MSB->LSB, to find H = hi-word of 30th smallest
    #pragma unroll
    for (int p = 0; p < 4; ++p) {
        int shift = 24 - 8 * p;
        sHist[tid] = 0u;
        __syncthreads();                       // publishes sPrefix/sRem too
        unsigned int pref = sPrefix;
        #pragma unroll
        for (int t = 0; t < 32; ++t) {
            unsigned int k = khi[t];
            bool in = (p == 0) || ((k >> (shift + 8)) == (pref >> (shift + 8)));
            if (in) atomicAdd(&sHist[(k >> shift) & 255u], 1u);
        }
        __syncthreads();
        if (tid < 64) {
            unsigned int b0 = sHist[tid * 4 + 0];
            unsigned int b1 = sHist[tid * 4 + 1];
            unsigned int b2 = sHist[tid * 4 + 2];
            unsigned int b3 = sHist[tid * 4 + 3];
            unsigned int s4 = b0 + b1 + b2 + b3;
            unsigned int sc = s4;
            #pragma unroll
            for (int off = 1; off < 64; off <<= 1) {
                unsigned int u = __shfl_up(sc, off);
                if (tid >= off) sc += u;
            }
            unsigned int excl = sc - s4;
            unsigned int rem = sRem;
            bool hit = (rem >= excl) && (rem < sc);
            if (hit) {
                unsigned int r2 = rem - excl;
                int bin; unsigned int sub;
                if (r2 < b0)                { bin = 0; sub = 0; }
                else if (r2 < b0 + b1)      { bin = 1; sub = b0; }
                else if (r2 < b0 + b1 + b2) { bin = 2; sub = b0 + b1; }
                else                        { bin = 3; sub = b0 + b1 + b2; }
                sPrefix = pref | ((unsigned int)(tid * 4 + bin) << shift);
                sRem = r2 - sub;
            }
        }
        __syncthreads();
    }

    // collect all keys with hi <= H (>= 30 items, typically 30)
    unsigned int H = sPrefix;
    #pragma unroll
    for (int t = 0; t < 32; ++t) {
        if (khi[t] <= H) {
            int j = tid + (t << 8);
            unsigned int pos = atomicAdd(&sCnt, 1u);
            if (pos < 64) {
                unsigned long long full = dist_key(CaP, j, cax, cay, caz);
                if (mi * mask[j] == 0.0f) full = 0xFFFFFFFFFFFFFFFFull;
                sCandKey[pos] = full;
                sCandIdx[pos] = j;
            }
        }
    }
    __syncthreads();

    // rank-sort candidates on wave 0; emit first 30 in ascending (key, idx) order
    if (tid < 64) {
        int n = (int)sCnt; if (n > 64) n = 64;
        if (tid < n) {
            unsigned long long myk = sCandKey[tid];
            int myi = sCandIdx[tid];
            int rank = 0;
            for (int u = 0; u < n; ++u) {
                unsigned long long ku = sCandKey[u];
                int iu = sCandIdx[u];
                rank += (ku < myk || (ku == myk && iu < myi)) ? 1 : 0;
            }
            if (rank < TOPK) {
                eidx[row * TOPK + rank] = myi;
                eidx_f[row * TOPK + rank] = (float)myi;
            }
        }
    }
}

// ---------------------------------------------------------------- edge features + fp16 MFMA GEMM + LN
// WG = 256 (4 waves) x 64 edges. Wave w: 16 edges (rows w*16..+15) x all 128 cols.
// A (RBF) generated in-register per K-step; B (W2 fp16 col-major) from global (L2-hot).
__global__ __launch_bounds__(256, 4) void edge_kernel(const float* __restrict__ Y5,
                                                      const float* __restrict__ Tt,
                                                      const _Float16* __restrict__ Wt,
                                                      const int* __restrict__ eidx,
                                                      const int* __restrict__ residue_idx,
                                                      const int* __restrict__ chain_idx,
                                                      const float* __restrict__ ln_scale,
                                                      const float* __restrict__ ln_offset,
                                                      float* __restrict__ out) {
    __shared__ __attribute__((aligned(16))) float sDist[25][64];
    __shared__ int sD[64];

    int tid = threadIdx.x;
    int m0 = blockIdx.x * 64;

    // ---- phase 1: per-edge metadata + 25 atom-pair distances (4 threads per edge)
    {
        int e = tid >> 2, q = tid & 3;
        int m = m0 + e;
        int i = (int)((unsigned)m / 30u);
        int j = eidx[m];
        if (q == 0) {
            int off = residue_idx[i] - residue_idx[j];
            int same = (chain_idx[i] == chain_idx[j]) ? 1 : 0;
            int dcl = off + 32;
            dcl = dcl < 0 ? 0 : (dcl > 64 ? 64 : dcl);
            sD[e] = same ? dcl : 65;
        }
        float yi[15], yj[15];
        const float* pi = Y5 + i * 15;
        const float* pj = Y5 + j * 15;
        #pragma unroll
        for (int t = 0; t < 15; ++t) { yi[t] = pi[t]; yj[t] = pj[t]; }
        #pragma unroll
        for (int e25 = 0; e25 < 25; ++e25) {
            if ((e25 & 3) == q) {
                int a = c_ea[e25], b = c_eb[e25];
                float dx = yi[a * 3 + 0] - yj[b * 3 + 0];
                float dy = yi[a * 3 + 1] - yj[b * 3 + 1];
                float dz = yi[a * 3 + 2] - yj[b * 3 + 2];
                sDist[e25][e] = sqrtf(dx * dx + dy * dy + dz * dz + 1e-6f);
            }
        }
    }
    __syncthreads();

    int lane = tid & 63, wid = tid >> 6;
    int r0 = wid * 16;            // wave's edge-row base within the 64-edge tile
    int c = lane & 15;            // col-within-16-tile / A-row selector
    int g = lane >> 4;            // k-slot (A/B) and row-group (C/D)
    int ar = r0 + c;              // A row this lane feeds

    f32x4 acc[8];
    #pragma unroll
    for (int t = 0; t < 8; ++t) acc[t] = (f32x4){0.f, 0.f, 0.f, 0.f};

    const _Float16* wbase = Wt + (size_t)c * 424;

    #pragma unroll
    for (int s = 0; s < 13; ++s) {
        int k0 = s * 32 + g * 8;
        half8 af = {};
        if (k0 < 400) {
            int e25 = k0 >> 4, rr0 = k0 & 15;
            float dv = sDist[e25][ar];
            #pragma unroll
            for (int j2 = 0; j2 < 8; ++j2) {
                float mu = 2.0f + 1.33333333f * (float)(rr0 + j2);
                float x = (dv - mu) * 0.8f;
                af[j2] = (_Float16)__expf(-x * x);
            }
        }
        #pragma unroll
        for (int t = 0; t < 8; ++t) {
            half8 bf = *reinterpret_cast<const half8*>(wbase + t * 16 * 424 + k0);
            acc[t] = __builtin_amdgcn_mfma_f32_16x16x32_f16(af, bf, acc[t], 0, 0, 0);
        }
    }

    // ---- epilogue: +T, LayerNorm over 128 (16-lane shfl groups), store
    float ls[8], lo[8];
    #pragma unroll
    for (int t = 0; t < 8; ++t) {
        ls[t] = ln_scale[t * 16 + c];
        lo[t] = ln_offset[t * 16 + c];
    }
    #pragma unroll
    for (int j = 0; j < 4; ++j) {
        int r = r0 + g * 4 + j;          // edge row for this C/D reg
        int m = m0 + r;
        int dI = sD[r];
        float v[8];
        float sum = 0.f;
        #pragma unroll
        for (int t = 0; t < 8; ++t) {
            v[t] = acc[t][j] + Tt[dI * 128 + t * 16 + c];
            sum += v[t];
        }
        sum += __shfl_xor(sum, 1); sum += __shfl_xor(sum, 2);
        sum += __shfl_xor(sum, 4); sum += __shfl_xor(sum, 8);
        float mu = sum * (1.0f / 128.0f);
        float sq = 0.f;
        #pragma unroll
        for (int t = 0; t < 8; ++t) { v[t] -= mu; sq += v[t] * v[t]; }
        sq += __shfl_xor(sq, 1); sq += __shfl_xor(sq, 2);
        sq += __shfl_xor(sq, 4); sq += __shfl_xor(sq, 8);
        float rs = rsqrtf(sq * (1.0f / 128.0f) + 1e-5f);
        #pragma unroll
        for (int t = 0; t < 8; ++t)
            out[(size_t)m * 128 + t * 16 + c] = v[t] * rs * ls[t] + lo[t];
    }
}

extern "C" void kernel_launch(void* const* d_in, const int* in_sizes, int n_in,
                              void* d_out, int out_size, void* d_ws, size_t ws_size,
                              hipStream_t stream) {
    const float* X           = (const float*)d_in[0];
    const float* mask        = (const float*)d_in[1];
    const int*   residue_idx = (const int*)d_in[2];
    const int*   chain_idx   = (const int*)d_in[3];
    const float* pe_w        = (const float*)d_in[4];
    const float* pe_b        = (const float*)d_in[5];
    const float* edge_w      = (const float*)d_in[6];
    const float* ln_scale    = (const float*)d_in[7];
    const float* ln_offset   = (const float*)d_in[8];

    float* out = (float*)d_out;

    // workspace layout (bytes)
    char* base = (char*)d_ws;
    float*     Y5   = (float*)(base);              // 8192*15*4 = 491520
    float*     CaP  = (float*)(base + 491520);     // 8192*3*4  =  98304
    float*     Tt   = (float*)(base + 589824);     // 66*128*4  =  33792
    int*       eidx = (int*)  (base + 623616);     // 8192*30*4 = 983040
    _Float16*  Wt   = (_Float16*)(base + 1606656); // 128*424*2 = 108544

    float* E     = out;                 // 8192*30*128 floats
    float* eidxf = out + 31457280;      // 8192*30 floats (harness reads d_out as f32)

    prep_kernel<<<LRES / 256, 256, 0, stream>>>(X, Y5, CaP);
    pet_kernel<<<(66 * 128 + 255) / 256, 256, 0, stream>>>(pe_w, pe_b, edge_w, Tt);
    wcvt_kernel<<<(128 * 424 + 255) / 256, 256, 0, stream>>>(edge_w, Wt);
    topk_kernel<<<LRES, 256, 0, stream>>>(CaP, mask, eidx, eidxf);
    edge_kernel<<<(LRES * TOPK) / 64, 256, 0, stream>>>(Y5, Tt, Wt, eidx, residue_idx,
                                                        chain_idx, ln_scale, ln_offset, E);
}

// Round 5
// 676.073 us; speedup vs baseline: 1.4555x; 1.4555x over previous
//
#include <hip/hip_runtime.h>
#include <math.h>

#define LRES 8192
#define TOPK 30

typedef _Float16 half8 __attribute__((ext_vector_type(8)));
typedef float f32x4 __attribute__((ext_vector_type(4)));

// EDGES[:,0] (atom at residue i) and EDGES[:,1] (atom at neighbor j)
__device__ __constant__ int c_ea[25] = {1,0,2,3,4,1,1,1,1,0,0,0,4,4,3,0,2,3,4,2,3,4,2,3,2};
__device__ __constant__ int c_eb[25] = {1,0,2,3,4,0,2,3,4,2,3,4,2,3,2,1,1,1,1,0,0,0,4,4,3};

// ---------------------------------------------------------------- prep: Y5 + packed Ca
__global__ __launch_bounds__(256) void prep_kernel(const float* __restrict__ X,
                                                   float* __restrict__ Y5,
                                                   float* __restrict__ CaP) {
    int i = blockIdx.x * 256 + threadIdx.x;
    const float* x = X + i * 12;
    float N0 = x[0], N1 = x[1], N2 = x[2];
    float A0 = x[3], A1 = x[4], A2 = x[5];   // Ca
    float C0 = x[6], C1 = x[7], C2 = x[8];
    float O0 = x[9], O1 = x[10], O2 = x[11];
    float bx = A0 - N0, by = A1 - N1, bz = A2 - N2;
    float cx = C0 - A0, cy = C1 - A1, cz = C2 - A2;
    float rx = by * cz - bz * cy;
    float ry = bz * cx - bx * cz;
    float rz = bx * cy - by * cx;
    float Bx = -0.58273431f * rx + 0.56802827f * bx - 0.54067466f * cx + A0;
    float By = -0.58273431f * ry + 0.56802827f * by - 0.54067466f * cy + A1;
    float Bz = -0.58273431f * rz + 0.56802827f * bz - 0.54067466f * cz + A2;
    float* y = Y5 + i * 15;
    y[0] = N0; y[1] = N1; y[2] = N2;
    y[3] = A0; y[4] = A1; y[5] = A2;
    y[6] = C0; y[7] = C1; y[8] = C2;
    y[9] = O0; y[10] = O1; y[11] = O2;
    y[12] = Bx; y[13] = By; y[14] = Bz;
    CaP[i * 3 + 0] = A0; CaP[i * 3 + 1] = A1; CaP[i * 3 + 2] = A2;
}

// ------------------------------------------- positional table T[66][128] = (pe_w[d]+pe_b) @ W[0:16]
__global__ __launch_bounds__(256) void pet_kernel(const float* __restrict__ pe_w,
                                                  const float* __restrict__ pe_b,
                                                  const float* __restrict__ edge_w,
                                                  float* __restrict__ T) {
    int idx = blockIdx.x * 256 + threadIdx.x;
    if (idx >= 66 * 128) return;
    int d = idx >> 7, c = idx & 127;
    float acc = 0.f;
    #pragma unroll
    for (int r = 0; r < 16; ++r)
        acc += (pe_w[d * 16 + r] + pe_b[r]) * edge_w[r * 128 + c];
    T[idx] = acc;
}

// ------------------------------------------- W2 -> fp16 col-major [128][424], K padded 400->424 w/ 0
__global__ __launch_bounds__(256) void wcvt_kernel(const float* __restrict__ edge_w,
                                                   _Float16* __restrict__ Wt) {
    int idx = blockIdx.x * 256 + threadIdx.x;
    if (idx >= 128 * 424) return;
    int c = idx / 424, k = idx - c * 424;
    Wt[idx] = (k < 400) ? (_Float16)edge_w[(16 + k) * 128 + c] : (_Float16)0.0f;
}

// ---------------------------------------------------------------- exact top-30 per row: radix select
// 1024 threads/block, 8 keys/thread in registers (16 VGPR) -> no spill at any occupancy.
__global__ __launch_bounds__(1024) void topk_kernel(const float* __restrict__ CaP,
                                                    const float* __restrict__ mask,
                                                    int* __restrict__ eidx,
                                                    float* __restrict__ eidx_f) {
    int row = blockIdx.x;
    int tid = threadIdx.x;
    __shared__ unsigned int sHist[256];
    __shared__ unsigned int sPrefix, sRem, sCnt;
    __shared__ unsigned long long sCandKey[64];
    __shared__ int sCandIdx[64];

    double cax = (double)CaP[row * 3 + 0];
    double cay = (double)CaP[row * 3 + 1];
    double caz = (double)CaP[row * 3 + 2];
    float mi = mask[row];

    // full 64-bit keys, register-resident (8 x u64 = 16 VGPR)
    unsigned long long key[8];
    #pragma unroll
    for (int t = 0; t < 8; ++t) {
        int j = tid + (t << 10);
        double dx = (double)CaP[j * 3 + 0] - cax;
        double dy = (double)CaP[j * 3 + 1] - cay;
        double dz = (double)CaP[j * 3 + 2] - caz;
        double s = dx * dx + dy * dy + dz * dz;   // >=0: bit pattern order-monotone
        unsigned long long kb = (unsigned long long)__double_as_longlong(s);
        if (mi * mask[j] == 0.0f) kb = 0xFFFFFFFFFFFFFFFFull;
        key[t] = kb;
    }
    if (tid == 0) { sPrefix = 0u; sRem = TOPK - 1; sCnt = 0u; }

    // 4 radix passes, 8 bits MSB->LSB, over hi-32 of key: find H = hi-word of 30th smallest
    #pragma unroll
    for (int p = 0; p < 4; ++p) {
        int shift = 24 - 8 * p;
        if (tid < 256) sHist[tid] = 0u;
        __syncthreads();                       // publishes sPrefix/sRem too
        unsigned int pref = sPrefix;
        #pragma unroll
        for (int t = 0; t < 8; ++t) {
            unsigned int k = (unsigned int)(key[t] >> 32);
            bool in = (p == 0) || ((k >> (shift + 8)) == (pref >> (shift + 8)));
            if (in) atomicAdd(&sHist[(k >> shift) & 255u], 1u);
        }
        __syncthreads();
        if (tid < 64) {
            unsigned int b0 = sHist[tid * 4 + 0];
            unsigned int b1 = sHist[tid * 4 + 1];
            unsigned int b2 = sHist[tid * 4 + 2];
            unsigned int b3 = sHist[tid * 4 + 3];
            unsigned int s4 = b0 + b1 + b2 + b3;
            unsigned int sc = s4;
            #pragma unroll
            for (int off = 1; off < 64; off <<= 1) {
                unsigned int u = __shfl_up(sc, off);
                if (tid >= off) sc += u;
            }
            unsigned int excl = sc - s4;
            unsigned int rem = sRem;
            bool hit = (rem >= excl) && (rem < sc);
            if (hit) {
                unsigned int r2 = rem - excl;
                int bin; unsigned int sub;
                if (r2 < b0)                { bin = 0; sub = 0; }
                else if (r2 < b0 + b1)      { bin = 1; sub = b0; }
                else if (r2 < b0 + b1 + b2) { bin = 2; sub = b0 + b1; }
                else                        { bin = 3; sub = b0 + b1 + b2; }
                sPrefix = pref | ((unsigned int)(tid * 4 + bin) << shift);
                sRem = r2 - sub;
            }
        }
        __syncthreads();
    }

    // collect all keys with hi <= H (>= 30 items, typically ~30)
    unsigned int H = sPrefix;
    #pragma unroll
    for (int t = 0; t < 8; ++t) {
        if ((unsigned int)(key[t] >> 32) <= H) {
            int j = tid + (t << 10);
            unsigned int pos = atomicAdd(&sCnt, 1u);
            if (pos < 64) {
                sCandKey[pos] = key[t];
                sCandIdx[pos] = j;
            }
        }
    }
    __syncthreads();

    // rank-sort candidates on wave 0; emit first 30 in ascending (key, idx) order
    if (tid < 64) {
        int n = (int)sCnt; if (n > 64) n = 64;
        if (tid < n) {
            unsigned long long myk = sCandKey[tid];
            int myi = sCandIdx[tid];
            int rank = 0;
            for (int u = 0; u < n; ++u) {
                unsigned long long ku = sCandKey[u];
                int iu = sCandIdx[u];
                rank += (ku < myk || (ku == myk && iu < myi)) ? 1 : 0;
            }
            if (rank < TOPK) {
                eidx[row * TOPK + rank] = myi;
                eidx_f[row * TOPK + rank] = (float)myi;
            }
        }
    }
}

// ---------------------------------------------------------------- edge features + fp16 MFMA GEMM + LN
// WG = 256 (4 waves) x 64 edges. Wave w: 16 edges (rows w*16..+15) x all 128 cols.
// A (RBF) generated in-register per K-step; B (W2 fp16 col-major) from global (L2-hot).
__global__ __launch_bounds__(256, 4) void edge_kernel(const float* __restrict__ Y5,
                                                      const float* __restrict__ Tt,
                                                      const _Float16* __restrict__ Wt,
                                                      const int* __restrict__ eidx,
                                                      const int* __restrict__ residue_idx,
                                                      const int* __restrict__ chain_idx,
                                                      const float* __restrict__ ln_scale,
                                                      const float* __restrict__ ln_offset,
                                                      float* __restrict__ out) {
    __shared__ __attribute__((aligned(16))) float sDist[25][64];
    __shared__ int sD[64];

    int tid = threadIdx.x;
    int m0 = blockIdx.x * 64;

    // ---- phase 1: per-edge metadata + 25 atom-pair distances (4 threads per edge)
    {
        int e = tid >> 2, q = tid & 3;
        int m = m0 + e;
        int i = (int)((unsigned)m / 30u);
        int j = eidx[m];
        if (q == 0) {
            int off = residue_idx[i] - residue_idx[j];
            int same = (chain_idx[i] == chain_idx[j]) ? 1 : 0;
            int dcl = off + 32;
            dcl = dcl < 0 ? 0 : (dcl > 64 ? 64 : dcl);
            sD[e] = same ? dcl : 65;
        }
        float yi[15], yj[15];
        const float* pi = Y5 + i * 15;
        const float* pj = Y5 + j * 15;
        #pragma unroll
        for (int t = 0; t < 15; ++t) { yi[t] = pi[t]; yj[t] = pj[t]; }
        #pragma unroll
        for (int e25 = 0; e25 < 25; ++e25) {
            if ((e25 & 3) == q) {
                int a = c_ea[e25], b = c_eb[e25];
                float dx = yi[a * 3 + 0] - yj[b * 3 + 0];
                float dy = yi[a * 3 + 1] - yj[b * 3 + 1];
                float dz = yi[a * 3 + 2] - yj[b * 3 + 2];
                sDist[e25][e] = sqrtf(dx * dx + dy * dy + dz * dz + 1e-6f);
            }
        }
    }
    __syncthreads();

    int lane = tid & 63, wid = tid >> 6;
    int r0 = wid * 16;            // wave's edge-row base within the 64-edge tile
    int c = lane & 15;            // col-within-16-tile / A-row selector
    int g = lane >> 4;            // k-slot (A/B) and row-group (C/D)
    int ar = r0 + c;              // A row this lane feeds

    f32x4 acc[8];
    #pragma unroll
    for (int t = 0; t < 8; ++t) acc[t] = (f32x4){0.f, 0.f, 0.f, 0.f};

    const _Float16* wbase = Wt + (size_t)c * 424;

    #pragma unroll
    for (int s = 0; s < 13; ++s) {
        int k0 = s * 32 + g * 8;
        half8 af = {};
        if (k0 < 400) {
            int e25 = k0 >> 4, rr0 = k0 & 15;
            float dv = sDist[e25][ar];
            #pragma unroll
            for (int j2 = 0; j2 < 8; ++j2) {
                float mu = 2.0f + 1.33333333f * (float)(rr0 + j2);
                float x = (dv - mu) * 0.8f;
                af[j2] = (_Float16)__expf(-x * x);
            }
        }
        #pragma unroll
        for (int t = 0; t < 8; ++t) {
            half8 bf = *reinterpret_cast<const half8*>(wbase + t * 16 * 424 + k0);
            acc[t] = __builtin_amdgcn_mfma_f32_16x16x32_f16(af, bf, acc[t], 0, 0, 0);
        }
    }

    // ---- epilogue: +T, LayerNorm over 128 (16-lane shfl groups), store
    float ls[8], lo[8];
    #pragma unroll
    for (int t = 0; t < 8; ++t) {
        ls[t] = ln_scale[t * 16 + c];
        lo[t] = ln_offset[t * 16 + c];
    }
    #pragma unroll
    for (int j = 0; j < 4; ++j) {
        int r = r0 + g * 4 + j;          // edge row for this C/D reg
        int m = m0 + r;
        int dI = sD[r];
        float v[8];
        float sum = 0.f;
        #pragma unroll
        for (int t = 0; t < 8; ++t) {
            v[t] = acc[t][j] + Tt[dI * 128 + t * 16 + c];
            sum += v[t];
        }
        sum += __shfl_xor(sum, 1); sum += __shfl_xor(sum, 2);
        sum += __shfl_xor(sum, 4); sum += __shfl_xor(sum, 8);
        float mu = sum * (1.0f / 128.0f);
        float sq = 0.f;
        #pragma unroll
        for (int t = 0; t < 8; ++t) { v[t] -= mu; sq += v[t] * v[t]; }
        sq += __shfl_xor(sq, 1); sq += __shfl_xor(sq, 2);
        sq += __shfl_xor(sq, 4); sq += __shfl_xor(sq, 8);
        float rs = rsqrtf(sq * (1.0f / 128.0f) + 1e-5f);
        #pragma unroll
        for (int t = 0; t < 8; ++t)
            out[(size_t)m * 128 + t * 16 + c] = v[t] * rs * ls[t] + lo[t];
    }
}

extern "C" void kernel_launch(void* const* d_in, const int* in_sizes, int n_in,
                              void* d_out, int out_size, void* d_ws, size_t ws_size,
                              hipStream_t stream) {
    const float* X           = (const float*)d_in[0];
    const float* mask        = (const float*)d_in[1];
    const int*   residue_idx = (const int*)d_in[2];
    const int*   chain_idx   = (const int*)d_in[3];
    const float* pe_w        = (const float*)d_in[4];
    const float* pe_b        = (const float*)d_in[5];
    const float* edge_w      = (const float*)d_in[6];
    const float* ln_scale    = (const float*)d_in[7];
    const float* ln_offset   = (const float*)d_in[8];

    float* out = (float*)d_out;

    // workspace layout (bytes)
    char* base = (char*)d_ws;
    float*     Y5   = (float*)(base);              // 8192*15*4 = 491520
    float*     CaP  = (float*)(base + 491520);     // 8192*3*4  =  98304
    float*     Tt   = (float*)(base + 589824);     // 66*128*4  =  33792
    int*       eidx = (int*)  (base + 623616);     // 8192*30*4 = 983040
    _Float16*  Wt   = (_Float16*)(base + 1606656); // 128*424*2 = 108544

    float* E     = out;                 // 8192*30*128 floats
    float* eidxf = out + 31457280;      // 8192*30 floats (harness reads d_out as f32)

    prep_kernel<<<LRES / 256, 256, 0, stream>>>(X, Y5, CaP);
    pet_kernel<<<(66 * 128 + 255) / 256, 256, 0, stream>>>(pe_w, pe_b, edge_w, Tt);
    wcvt_kernel<<<(128 * 424 + 255) / 256, 256, 0, stream>>>(edge_w, Wt);
    topk_kernel<<<LRES, 1024, 0, stream>>>(CaP, mask, eidx, eidxf);
    edge_kernel<<<(LRES * TOPK) / 64, 256, 0, stream>>>(Y5, Tt, Wt, eidx, residue_idx,
                                                        chain_idx, ln_scale, ln_offset, E);
}

// Round 8
// 381.013 us; speedup vs baseline: 2.5827x; 1.7744x over previous
//
#include <hip/hip_runtime.h>
#include <math.h>

#define LRES 8192
#define TOPK 30
#define CAND 192

typedef _Float16 half8 __attribute__((ext_vector_type(8)));
typedef float f32x4 __attribute__((ext_vector_type(4)));

// EDGES[:,0] (atom at residue i) and EDGES[:,1] (atom at neighbor j)
__device__ __constant__ int c_ea[25] = {1,0,2,3,4,1,1,1,1,0,0,0,4,4,3,0,2,3,4,2,3,4,2,3,2};
__device__ __constant__ int c_eb[25] = {1,0,2,3,4,0,2,3,4,2,3,4,2,3,2,1,1,1,1,0,0,0,4,4,3};

// ---------------------------------------------------------------- prep: Y5 + packed Ca
__global__ __launch_bounds__(256) void prep_kernel(const float* __restrict__ X,
                                                   float* __restrict__ Y5,
                                                   float* __restrict__ CaP) {
    int i = blockIdx.x * 256 + threadIdx.x;
    const float* x = X + i * 12;
    float N0 = x[0], N1 = x[1], N2 = x[2];
    float A0 = x[3], A1 = x[4], A2 = x[5];   // Ca
    float C0 = x[6], C1 = x[7], C2 = x[8];
    float O0 = x[9], O1 = x[10], O2 = x[11];
    float bx = A0 - N0, by = A1 - N1, bz = A2 - N2;
    float cx = C0 - A0, cy = C1 - A1, cz = C2 - A2;
    float rx = by * cz - bz * cy;
    float ry = bz * cx - bx * cz;
    float rz = bx * cy - by * cx;
    float Bx = -0.58273431f * rx + 0.56802827f * bx - 0.54067466f * cx + A0;
    float By = -0.58273431f * ry + 0.56802827f * by - 0.54067466f * cy + A1;
    float Bz = -0.58273431f * rz + 0.56802827f * bz - 0.54067466f * cz + A2;
    float* y = Y5 + i * 15;
    y[0] = N0; y[1] = N1; y[2] = N2;
    y[3] = A0; y[4] = A1; y[5] = A2;
    y[6] = C0; y[7] = C1; y[8] = C2;
    y[9] = O0; y[10] = O1; y[11] = O2;
    y[12] = Bx; y[13] = By; y[14] = Bz;
    CaP[i * 3 + 0] = A0; CaP[i * 3 + 1] = A1; CaP[i * 3 + 2] = A2;
}

// ------------------------------------------- positional table T[66][128] = (pe_w[d]+pe_b) @ W[0:16]
__global__ __launch_bounds__(256) void pet_kernel(const float* __restrict__ pe_w,
                                                  const float* __restrict__ pe_b,
                                                  const float* __restrict__ edge_w,
                                                  float* __restrict__ T) {
    int idx = blockIdx.x * 256 + threadIdx.x;
    if (idx >= 66 * 128) return;
    int d = idx >> 7, c = idx & 127;
    float acc = 0.f;
    #pragma unroll
    for (int r = 0; r < 16; ++r)
        acc += (pe_w[d * 16 + r] + pe_b[r]) * edge_w[r * 128 + c];
    T[idx] = acc;
}

// ------------------------------------------- W2 -> fp16 fragment-major Wf[s][t][g][lane(c)][j2]
// half index: (((s*8+t)*4+g)*16 + c)*8 + j2  maps  (k = s*32+g*8+j2, col = t*16+c)
__global__ __launch_bounds__(256) void wcvt_kernel(const float* __restrict__ edge_w,
                                                   _Float16* __restrict__ Wf) {
    int idx = blockIdx.x * 256 + threadIdx.x;
    if (idx >= 13 * 8 * 4 * 16 * 8) return;
    int j2 = idx & 7;
    int c  = (idx >> 3) & 15;
    int g  = (idx >> 7) & 3;
    int t  = (idx >> 9) & 7;
    int s  = idx >> 12;
    int k   = s * 32 + g * 8 + j2;
    int col = t * 16 + c;
    Wf[idx] = (k < 400) ? (_Float16)edge_w[(16 + k) * 128 + col] : (_Float16)0.0f;
}

// ---------------------------------------------------------------- exact top-30: log-histogram select
// 1024 threads, 8 u64 keys/thread in registers. One 256-bin histogram over
// quarter-octave log2(d^2/ref) bins (ref = 2nd-smallest hi-word) -> spread bins,
// low atomic contention. Collect bins <= B, exact f64 rank-sort of ~35 candidates.
__global__ __launch_bounds__(1024) void topk_kernel(const float* __restrict__ CaP,
                                                    const float* __restrict__ mask,
                                                    int* __restrict__ eidx,
                                                    float* __restrict__ eidx_f) {
    int row = blockIdx.x;
    int tid = threadIdx.x;
    int lane = tid & 63, wid = tid >> 6;
    __shared__ unsigned int sHist[256];
    __shared__ unsigned int sMin[32];
    __shared__ unsigned int sRef, sB, sCnt;
    __shared__ unsigned long long sCandKey[CAND];
    __shared__ int sCandIdx[CAND];

    double cax = (double)CaP[row * 3 + 0];
    double cay = (double)CaP[row * 3 + 1];
    double caz = (double)CaP[row * 3 + 2];
    float mi = mask[row];

    unsigned long long key[8];
    #pragma unroll
    for (int t = 0; t < 8; ++t) {
        int j = tid + (t << 10);
        double dx = (double)CaP[j * 3 + 0] - cax;
        double dy = (double)CaP[j * 3 + 1] - cay;
        double dz = (double)CaP[j * 3 + 2] - caz;
        double s = dx * dx + dy * dy + dz * dz;   // >=0: bit pattern order-monotone
        unsigned long long kb = (unsigned long long)__double_as_longlong(s);
        if (mi * mask[j] == 0.0f) kb = 0xFFFFFFFFFFFFFFFFull;
        key[t] = kb;
    }

    // ---- block-wide (min1, min2) of hi-32 words
    unsigned int m1 = 0xFFFFFFFFu, m2 = 0xFFFFFFFFu;
    #pragma unroll
    for (int t = 0; t < 8; ++t) {
        unsigned int h = (unsigned int)(key[t] >> 32);
        if (h < m1) { m2 = m1; m1 = h; }
        else if (h < m2) { m2 = h; }
    }
    #pragma unroll
    for (int off = 1; off < 64; off <<= 1) {
        unsigned int o1 = __shfl_xor(m1, off);
        unsigned int o2 = __shfl_xor(m2, off);
        unsigned int lo = m1 < o1 ? m1 : o1;
        unsigned int hx = m1 < o1 ? o1 : m1;
        unsigned int oo = m2 < o2 ? m2 : o2;
        m2 = hx < oo ? hx : oo;
        m1 = lo;
    }
    if (lane == 0) { sMin[wid * 2] = m1; sMin[wid * 2 + 1] = m2; }
    if (tid < 256) sHist[tid] = 0u;
    if (tid == 0) sCnt = 0u;
    __syncthreads();
    if (tid == 0) {
        unsigned int M1 = 0xFFFFFFFFu, M2 = 0xFFFFFFFFu;
        for (int w = 0; w < 16; ++w) {
            unsigned int a = sMin[w * 2], b = sMin[w * 2 + 1];
            unsigned int lo = M1 < a ? M1 : a;
            unsigned int hx = M1 < a ? a : M1;
            unsigned int oo = M2 < b ? M2 : b;
            M2 = hx < oo ? hx : oo;
            M1 = lo;
        }
        sRef = M2;
    }
    __syncthreads();
    unsigned int ref = sRef;

    // ---- histogram over quarter-octave bins
    #pragma unroll
    for (int t = 0; t < 8; ++t) {
        unsigned int h = (unsigned int)(key[t] >> 32);
        unsigned int bin = (h <= ref) ? 0u : ((h - ref) >> 18);
        if (bin > 255u) bin = 255u;
        atomicAdd(&sHist[bin], 1u);
    }
    __syncthreads();

    // ---- scan (wave 0): find first bin B with inclusive-cum >= TOPK
    if (tid < 64) {
        unsigned int b0 = sHist[tid * 4 + 0];
        unsigned int b1 = sHist[tid * 4 + 1];
        unsigned int b2 = sHist[tid * 4 + 2];
        unsigned int b3 = sHist[tid * 4 + 3];
        unsigned int s4 = b0 + b1 + b2 + b3;
        unsigned int sc = s4;
        #pragma unroll
        for (int off = 1; off < 64; off <<= 1) {
            unsigned int u = __shfl_up(sc, off);
            if (tid >= off) sc += u;
        }
        unsigned int excl = sc - s4;
        if (excl < TOPK && sc >= TOPK) {
            unsigned int c0 = excl + b0, c1 = c0 + b1, c2 = c1 + b2;
            int bsel = (c0 >= TOPK) ? 0 : (c1 >= TOPK) ? 1 : (c2 >= TOPK) ? 2 : 3;
            sB = (unsigned int)(tid * 4 + bsel);
        }
    }
    __syncthreads();
    unsigned int B = sB;

    // ---- collect candidates (bin <= B  =>  superset of exact top-30)
    #pragma unroll
    for (int t = 0; t < 8; ++t) {
        unsigned int h = (unsigned int)(key[t] >> 32);
        unsigned int bin = (h <= ref) ? 0u : ((h - ref) >> 18);
        if (bin > 255u) bin = 255u;
        if (bin <= B) {
            unsigned int pos = atomicAdd(&sCnt, 1u);
            if (pos < CAND) {
                sCandKey[pos] = key[t];
                sCandIdx[pos] = tid + (t << 10);
            }
        }
    }
    __syncthreads();

    // ---- exact rank-sort on full f64 keys; emit ascending (key, idx)
    int n = (int)sCnt; if (n > CAND) n = CAND;
    if (tid < n) {
        unsigned long long myk = sCandKey[tid];
        int myi = sCandIdx[tid];
        int rank = 0;
        for (int u = 0; u < n; ++u) {
            unsigned long long ku = sCandKey[u];
            int iu = sCandIdx[u];
            rank += (ku < myk || (ku == myk && iu < myi)) ? 1 : 0;
        }
        if (rank < TOPK) {
            eidx[row * TOPK + rank] = myi;
            eidx_f[row * TOPK + rank] = (float)myi;
        }
    }
}

// ---------------------------------------------------------------- edge features + fp16 MFMA GEMM + LN
// Block = 256 threads = 4 waves, 128 edges. Wave: 32 edges (two 16-row A tiles) x 128 cols.
// B fragments from fragment-major Wf: each wave load = linear 1KB (coalesced, L1/L2-hot).
__global__ __launch_bounds__(256, 4) void edge_kernel(const float* __restrict__ Y5,
                                                      const float* __restrict__ Tt,
                                                      const half8* __restrict__ Wf,
                                                      const int* __restrict__ eidx,
                                                      const int* __restrict__ residue_idx,
                                                      const int* __restrict__ chain_idx,
                                                      const float* __restrict__ ln_scale,
                                                      const float* __restrict__ ln_offset,
                                                      float* __restrict__ out) {
    __shared__ __attribute__((aligned(16))) float sDist[25][128];
    __shared__ int sD[128];

    int tid = threadIdx.x;
    int m0 = blockIdx.x * 128;

    // ---- phase 1: per-edge metadata + 25 atom-pair distances (2 threads per edge)
    {
        int e = tid >> 1, q = tid & 1;
        int m = m0 + e;
        int i = (int)((unsigned)m / 30u);
        int j = eidx[m];
        if (q == 0) {
            int off = residue_idx[i] - residue_idx[j];
            int same = (chain_idx[i] == chain_idx[j]) ? 1 : 0;
            int dcl = off + 32;
            dcl = dcl < 0 ? 0 : (dcl > 64 ? 64 : dcl);
            sD[e] = same ? dcl : 65;
        }
        float yi[15], yj[15];
        const float* pi = Y5 + i * 15;
        const float* pj = Y5 + j * 15;
        #pragma unroll
        for (int t = 0; t < 15; ++t) { yi[t] = pi[t]; yj[t] = pj[t]; }
        #pragma unroll
        for (int e25 = 0; e25 < 25; ++e25) {
            if ((e25 & 1) == q) {
                int a = c_ea[e25], b = c_eb[e25];
                float dx = yi[a * 3 + 0] - yj[b * 3 + 0];
                float dy = yi[a * 3 + 1] - yj[b * 3 + 1];
                float dz = yi[a * 3 + 2] - yj[b * 3 + 2];
                sDist[e25][e] = sqrtf(dx * dx + dy * dy + dz * dz + 1e-6f);
            }
        }
    }
    __syncthreads();

    int lane = tid & 63, wid = tid >> 6;
    int we0 = wid * 32;           // wave's edge base within the 128-edge tile
    int c = lane & 15;            // A-row / B-col selector
    int g = lane >> 4;            // k-slot and C/D row-group
    int ar0 = we0 + c;            // A rows for the two 16-row tiles
    int ar1 = we0 + 16 + c;

    f32x4 acc0[8], acc1[8];
    #pragma unroll
    for (int t = 0; t < 8; ++t) { acc0[t] = (f32x4){0.f,0.f,0.f,0.f}; acc1[t] = (f32x4){0.f,0.f,0.f,0.f}; }

    #pragma unroll
    for (int s = 0; s < 13; ++s) {
        int k0 = s * 32 + g * 8;
        half8 af0 = {}, af1 = {};
        if (k0 < 400) {
            int e25 = k0 >> 4, rr0 = k0 & 15;
            float d0 = sDist[e25][ar0];
            float d1 = sDist[e25][ar1];
            #pragma unroll
            for (int j2 = 0; j2 < 8; ++j2) {
                float mu = 2.0f + 1.33333333f * (float)(rr0 + j2);
                float x0 = (d0 - mu) * 0.8f;
                float x1 = (d1 - mu) * 0.8f;
                af0[j2] = (_Float16)__expf(-x0 * x0);
                af1[j2] = (_Float16)__expf(-x1 * x1);
            }
        }
        const half8* wf = Wf + (size_t)s * 512 + g * 16 + c;   // + t*64 per col-tile
        #pragma unroll
        for (int t = 0; t < 8; ++t) {
            half8 bf = wf[t * 64];
            acc0[t] = __builtin_amdgcn_mfma_f32_16x16x32_f16(af0, bf, acc0[t], 0, 0, 0);
            acc1[t] = __builtin_amdgcn_mfma_f32_16x16x32_f16(af1, bf, acc1[t], 0, 0, 0);
        }
    }

    // ---- epilogue: +T, LayerNorm over 128 (16-lane shfl groups), store
    float ls[8], lo[8];
    #pragma unroll
    for (int t = 0; t < 8; ++t) {
        ls[t] = ln_scale[t * 16 + c];
        lo[t] = ln_offset[t * 16 + c];
    }
    #pragma unroll
    for (int a = 0; a < 2; ++a) {
        #pragma unroll
        for (int j = 0; j < 4; ++j) {
            int r = we0 + a * 16 + g * 4 + j;    // edge row for this C/D reg
            int m = m0 + r;
            int dI = sD[r];
            float v[8];
            float sum = 0.f;
            #pragma unroll
            for (int t = 0; t < 8; ++t) {
                float av = a ? acc1[t][j] : acc0[t][j];
                v[t] = av + Tt[dI * 128 + t * 16 + c];
                sum += v[t];
            }
            sum += __shfl_xor(sum, 1); sum += __shfl_xor(sum, 2);
            sum += __shfl_xor(sum, 4); sum += __shfl_xor(sum, 8);
            float mu = sum * (1.0f / 128.0f);
            float sq = 0.f;
            #pragma unroll
            for (int t = 0; t < 8; ++t) { v[t] -= mu; sq += v[t] * v[t]; }
            sq += __shfl_xor(sq, 1); sq += __shfl_xor(sq, 2);
            sq += __shfl_xor(sq, 4); sq += __shfl_xor(sq, 8);
            float rs = rsqrtf(sq * (1.0f / 128.0f) + 1e-5f);
            #pragma unroll
            for (int t = 0; t < 8; ++t)
                out[(size_t)m * 128 + t * 16 + c] = v[t] * rs * ls[t] + lo[t];
        }
    }
}

extern "C" void kernel_launch(void* const* d_in, const int* in_sizes, int n_in,
                              void* d_out, int out_size, void* d_ws, size_t ws_size,
                              hipStream_t stream) {
    const float* X           = (const float*)d_in[0];
    const float* mask        = (const float*)d_in[1];
    const int*   residue_idx = (const int*)d_in[2];
    const int*   chain_idx   = (const int*)d_in[3];
    const float* pe_w        = (const float*)d_in[4];
    const float* pe_b        = (const float*)d_in[5];
    const float* edge_w      = (const float*)d_in[6];
    const float* ln_scale    = (const float*)d_in[7];
    const float* ln_offset   = (const float*)d_in[8];

    float* out = (float*)d_out;

    // workspace layout (bytes)
    char* base = (char*)d_ws;
    float*     Y5   = (float*)(base);              // 8192*15*4 = 491520
    float*     CaP  = (float*)(base + 491520);     // 8192*3*4  =  98304
    float*     Tt   = (float*)(base + 589824);     // 66*128*4  =  33792
    int*       eidx = (int*)  (base + 623616);     // 8192*30*4 = 983040
    _Float16*  Wf   = (_Float16*)(base + 1606656); // 13*8*4*16*8*2 = 106496

    float* E     = out;                 // 8192*30*128 floats
    float* eidxf = out + 31457280;      // 8192*30 floats (harness reads d_out as f32)

    prep_kernel<<<LRES / 256, 256, 0, stream>>>(X, Y5, CaP);
    pet_kernel<<<(66 * 128 + 255) / 256, 256, 0, stream>>>(pe_w, pe_b, edge_w, Tt);
    wcvt_kernel<<<(13 * 8 * 4 * 16 * 8 + 255) / 256, 256, 0, stream>>>(edge_w, Wf);
    topk_kernel<<<LRES, 1024, 0, stream>>>(CaP, mask, eidx, eidxf);
    edge_kernel<<<(LRES * TOPK) / 128, 256, 0, stream>>>(Y5, Tt, (const half8*)Wf, eidx,
                                                         residue_idx, chain_idx,
                                                         ln_scale, ln_offset, E);
}

// Round 15
// 325.823 us; speedup vs baseline: 3.0202x; 1.1694x over previous
//
#include <hip/hip_runtime.h>
#include <math.h>

#define LRES 8192
#define TOPK 30
#define CAND 192

typedef _Float16 half8 __attribute__((ext_vector_type(8)));
typedef float f32x4 __attribute__((ext_vector_type(4)));

// EDGES[:,0] (atom at residue i) and EDGES[:,1] (atom at neighbor j)
__device__ __constant__ int c_ea[25] = {1,0,2,3,4,1,1,1,1,0,0,0,4,4,3,0,2,3,4,2,3,4,2,3,2};
__device__ __constant__ int c_eb[25] = {1,0,2,3,4,0,2,3,4,2,3,4,2,3,2,1,1,1,1,0,0,0,4,4,3};

// ---------------------------------------------------------------- prep: Y5 + SoA Ca
__global__ __launch_bounds__(256) void prep_kernel(const float* __restrict__ X,
                                                   float* __restrict__ Y5,
                                                   float* __restrict__ Cx,
                                                   float* __restrict__ Cy,
                                                   float* __restrict__ Cz) {
    int i = blockIdx.x * 256 + threadIdx.x;
    const float* x = X + i * 12;
    float N0 = x[0], N1 = x[1], N2 = x[2];
    float A0 = x[3], A1 = x[4], A2 = x[5];   // Ca
    float C0 = x[6], C1 = x[7], C2 = x[8];
    float O0 = x[9], O1 = x[10], O2 = x[11];
    float bx = A0 - N0, by = A1 - N1, bz = A2 - N2;
    float cx = C0 - A0, cy = C1 - A1, cz = C2 - A2;
    float rx = by * cz - bz * cy;
    float ry = bz * cx - bx * cz;
    float rz = bx * cy - by * cx;
    float Bx = -0.58273431f * rx + 0.56802827f * bx - 0.54067466f * cx + A0;
    float By = -0.58273431f * ry + 0.56802827f * by - 0.54067466f * cy + A1;
    float Bz = -0.58273431f * rz + 0.56802827f * bz - 0.54067466f * cz + A2;
    float* y = Y5 + i * 15;
    y[0] = N0; y[1] = N1; y[2] = N2;
    y[3] = A0; y[4] = A1; y[5] = A2;
    y[6] = C0; y[7] = C1; y[8] = C2;
    y[9] = O0; y[10] = O1; y[11] = O2;
    y[12] = Bx; y[13] = By; y[14] = Bz;
    Cx[i] = A0; Cy[i] = A1; Cz[i] = A2;
}

// ------------------------------------------- positional table T[66][128] = (pe_w[d]+pe_b) @ W[0:16]
__global__ __launch_bounds__(256) void pet_kernel(const float* __restrict__ pe_w,
                                                  const float* __restrict__ pe_b,
                                                  const float* __restrict__ edge_w,
                                                  float* __restrict__ T) {
    int idx = blockIdx.x * 256 + threadIdx.x;
    if (idx >= 66 * 128) return;
    int d = idx >> 7, c = idx & 127;
    float acc = 0.f;
    #pragma unroll
    for (int r = 0; r < 16; ++r)
        acc += (pe_w[d * 16 + r] + pe_b[r]) * edge_w[r * 128 + c];
    T[idx] = acc;
}

// ------------------------------------------- W2 -> fp16 fragment-major Wf[s][t][g][lane(c)][j2]
// half index: (((s*8+t)*4+g)*16 + c)*8 + j2  maps  (k = s*32+g*8+j2, col = t*16+c)
__global__ __launch_bounds__(256) void wcvt_kernel(const float* __restrict__ edge_w,
                                                   _Float16* __restrict__ Wf) {
    int idx = blockIdx.x * 256 + threadIdx.x;
    if (idx >= 13 * 8 * 4 * 16 * 8) return;
    int j2 = idx & 7;
    int c  = (idx >> 3) & 15;
    int g  = (idx >> 7) & 3;
    int t  = (idx >> 9) & 7;
    int s  = idx >> 12;
    int k   = s * 32 + g * 8 + j2;
    int col = t * 16 + c;
    Wf[idx] = (k < 400) ? (_Float16)edge_w[(16 + k) * 128 + col] : (_Float16)0.0f;
}

// ---------------------------------------------------------------- exact top-30: f32 scan + f64 refine
// 512 threads, 16 f32-bit keys/thread in registers (16 VGPR -> high occupancy).
// Log-histogram (1/4-octave bins) over f32 key bits; collect bins <= B+1 (margin bin
// absorbs any f32-vs-f64 rounding swap at the rank-30 boundary); exact f64 keys
// recomputed for ~60 candidates; rank-sort emits ascending (key, idx).
__global__ __launch_bounds__(512) void topk_kernel(const float* __restrict__ Cx,
                                                   const float* __restrict__ Cy,
                                                   const float* __restrict__ Cz,
                                                   const float* __restrict__ mask,
                                                   int* __restrict__ eidx,
                                                   float* __restrict__ eidx_f) {
    int row = blockIdx.x;
    int tid = threadIdx.x;
    int lane = tid & 63, wid = tid >> 6;      // 8 waves
    __shared__ unsigned int sHist[256];
    __shared__ unsigned int sMin[16];
    __shared__ unsigned int sRef, sB, sCnt;
    __shared__ unsigned long long sKey[CAND];
    __shared__ int sIdx[CAND];

    float cx = Cx[row], cy = Cy[row], cz = Cz[row];
    float mi = mask[row];

    unsigned int ku[16];
    #pragma unroll
    for (int t = 0; t < 16; ++t) {
        int j = tid + (t << 9);
        float dx = Cx[j] - cx;
        float dy = Cy[j] - cy;
        float dz = Cz[j] - cz;
        float d2 = fmaf(dz, dz, fmaf(dy, dy, dx * dx));
        unsigned int u = __float_as_uint(d2);   // d2>=0: bits order-monotone
        if (mi * mask[j] == 0.0f) u = 0x7F800000u;   // +inf
        ku[t] = u;
    }

    // ---- block-wide (min1, min2) of key bits
    unsigned int m1 = 0xFFFFFFFFu, m2 = 0xFFFFFFFFu;
    #pragma unroll
    for (int t = 0; t < 16; ++t) {
        unsigned int h = ku[t];
        if (h < m1) { m2 = m1; m1 = h; }
        else if (h < m2) { m2 = h; }
    }
    #pragma unroll
    for (int off = 1; off < 64; off <<= 1) {
        unsigned int o1 = __shfl_xor(m1, off);
        unsigned int o2 = __shfl_xor(m2, off);
        unsigned int lo = m1 < o1 ? m1 : o1;
        unsigned int hx = m1 < o1 ? o1 : m1;
        unsigned int oo = m2 < o2 ? m2 : o2;
        m2 = hx < oo ? hx : oo;
        m1 = lo;
    }
    if (lane == 0) { sMin[wid * 2] = m1; sMin[wid * 2 + 1] = m2; }
    if (tid < 256) sHist[tid] = 0u;
    if (tid == 0) sCnt = 0u;
    __syncthreads();
    if (tid == 0) {
        unsigned int M1 = 0xFFFFFFFFu, M2 = 0xFFFFFFFFu;
        for (int w = 0; w < 8; ++w) {
            unsigned int a = sMin[w * 2], b = sMin[w * 2 + 1];
            unsigned int lo = M1 < a ? M1 : a;
            unsigned int hx = M1 < a ? a : M1;
            unsigned int oo = M2 < b ? M2 : b;
            M2 = hx < oo ? hx : oo;
            M1 = lo;
        }
        sRef = M2;    // 2nd-smallest (skips the self-point's ~0)
    }
    __syncthreads();
    unsigned int ref = sRef;

    // ---- histogram over quarter-octave bins (f32 exp step = 1<<23; >>21 -> 4 bins/octave)
    #pragma unroll
    for (int t = 0; t < 16; ++t) {
        unsigned int h = ku[t];
        unsigned int bin = (h <= ref) ? 0u : ((h - ref) >> 21);
        if (bin > 255u) bin = 255u;
        atomicAdd(&sHist[bin], 1u);
    }
    __syncthreads();

    // ---- scan (wave 0): first bin B with inclusive-cum >= TOPK
    if (tid < 64) {
        unsigned int b0 = sHist[tid * 4 + 0];
        unsigned int b1 = sHist[tid * 4 + 1];
        unsigned int b2 = sHist[tid * 4 + 2];
        unsigned int b3 = sHist[tid * 4 + 3];
        unsigned int s4 = b0 + b1 + b2 + b3;
        unsigned int sc = s4;
        #pragma unroll
        for (int off = 1; off < 64; off <<= 1) {
            unsigned int u = __shfl_up(sc, off);
            if (tid >= off) sc += u;
        }
        unsigned int excl = sc - s4;
        if (excl < TOPK && sc >= TOPK) {
            unsigned int c0 = excl + b0, c1 = c0 + b1, c2 = c1 + b2;
            int bsel = (c0 >= TOPK) ? 0 : (c1 >= TOPK) ? 1 : (c2 >= TOPK) ? 2 : 3;
            sB = (unsigned int)(tid * 4 + bsel);
        }
    }
    __syncthreads();
    unsigned int B = sB + 1u;          // +1 margin bin: f32/f64 rounding safety
    if (B > 255u) B = 255u;

    // ---- collect candidate indices (bins <= B  =>  superset of exact f64 top-30)
    #pragma unroll
    for (int t = 0; t < 16; ++t) {
        unsigned int h = ku[t];
        unsigned int bin = (h <= ref) ? 0u : ((h - ref) >> 21);
        if (bin > 255u) bin = 255u;
        if (bin <= B) {
            unsigned int pos = atomicAdd(&sCnt, 1u);
            if (pos < CAND) sIdx[pos] = tid + (t << 9);
        }
    }
    __syncthreads();

    // ---- exact f64 keys for candidates
    int n = (int)sCnt; if (n > CAND) n = CAND;
    if (tid < n) {
        int j = sIdx[tid];
        double dx = (double)Cx[j] - (double)cx;
        double dy = (double)Cy[j] - (double)cy;
        double dz = (double)Cz[j] - (double)cz;
        double s = dx * dx + dy * dy + dz * dz;
        unsigned long long kb = (unsigned long long)__double_as_longlong(s);
        if (mi * mask[j] == 0.0f) kb = 0xFFFFFFFFFFFFFFFFull;
        sKey[tid] = kb;
    }
    __syncthreads();

    // ---- rank-sort candidates; emit first 30 ascending (key, idx)
    if (tid < n) {
        unsigned long long myk = sKey[tid];
        int myi = sIdx[tid];
        int rank = 0;
        for (int u = 0; u < n; ++u) {
            unsigned long long ku2 = sKey[u];
            int iu = sIdx[u];
            rank += (ku2 < myk || (ku2 == myk && iu < myi)) ? 1 : 0;
        }
        if (rank < TOPK) {
            eidx[row * TOPK + rank] = myi;
            eidx_f[row * TOPK + rank] = (float)myi;
        }
    }
}

// ---------------------------------------------------------------- edge features + fp16 MFMA GEMM + LN
// Block = 256 threads = 4 waves, 128 edges. Wave: 32 edges (two 16-row A tiles) x 128 cols.
// B fragments from fragment-major Wf: each wave load = linear 1KB (coalesced, L1/L2-hot).
// No min-waves clause: let the allocator use ~120-160 VGPR without spilling.
__global__ __launch_bounds__(256) void edge_kernel(const float* __restrict__ Y5,
                                                   const float* __restrict__ Tt,
                                                   const half8* __restrict__ Wf,
                                                   const int* __restrict__ eidx,
                                                   const int* __restrict__ residue_idx,
                                                   const int* __restrict__ chain_idx,
                                                   const float* __restrict__ ln_scale,
                                                   const float* __restrict__ ln_offset,
                                                   float* __restrict__ out) {
    __shared__ __attribute__((aligned(16))) float sDist[25][128];
    __shared__ int sD[128];

    int tid = threadIdx.x;
    int m0 = blockIdx.x * 128;

    // ---- phase 1: per-edge metadata + 25 atom-pair distances (2 threads per edge)
    {
        int e = tid >> 1, q = tid & 1;
        int m = m0 + e;
        int i = (int)((unsigned)m / 30u);
        int j = eidx[m];
        if (q == 0) {
            int off = residue_idx[i] - residue_idx[j];
            int same = (chain_idx[i] == chain_idx[j]) ? 1 : 0;
            int dcl = off + 32;
            dcl = dcl < 0 ? 0 : (dcl > 64 ? 64 : dcl);
            sD[e] = same ? dcl : 65;
        }
        float yi[15], yj[15];
        const float* pi = Y5 + i * 15;
        const float* pj = Y5 + j * 15;
        #pragma unroll
        for (int t = 0; t < 15; ++t) { yi[t] = pi[t]; yj[t] = pj[t]; }
        #pragma unroll
        for (int e25 = 0; e25 < 25; ++e25) {
            if ((e25 & 1) == q) {
                int a = c_ea[e25], b = c_eb[e25];
                float dx = yi[a * 3 + 0] - yj[b * 3 + 0];
                float dy = yi[a * 3 + 1] - yj[b * 3 + 1];
                float dz = yi[a * 3 + 2] - yj[b * 3 + 2];
                sDist[e25][e] = sqrtf(dx * dx + dy * dy + dz * dz + 1e-6f);
            }
        }
    }
    __syncthreads();

    int lane = tid & 63, wid = tid >> 6;
    int we0 = wid * 32;           // wave's edge base within the 128-edge tile
    int c = lane & 15;            // A-row / B-col selector
    int g = lane >> 4;            // k-slot and C/D row-group
    int ar0 = we0 + c;            // A rows for the two 16-row tiles
    int ar1 = we0 + 16 + c;

    f32x4 acc0[8], acc1[8];
    #pragma unroll
    for (int t = 0; t < 8; ++t) { acc0[t] = (f32x4){0.f,0.f,0.f,0.f}; acc1[t] = (f32x4){0.f,0.f,0.f,0.f}; }

    #pragma unroll
    for (int s = 0; s < 13; ++s) {
        int k0 = s * 32 + g * 8;
        half8 af0 = {}, af1 = {};
        if (k0 < 400) {
            int e25 = k0 >> 4, rr0 = k0 & 15;
            float d0 = sDist[e25][ar0];
            float d1 = sDist[e25][ar1];
            #pragma unroll
            for (int j2 = 0; j2 < 8; ++j2) {
                float mu = 2.0f + 1.33333333f * (float)(rr0 + j2);
                float x0 = (d0 - mu) * 0.8f;
                float x1 = (d1 - mu) * 0.8f;
                af0[j2] = (_Float16)__expf(-x0 * x0);
                af1[j2] = (_Float16)__expf(-x1 * x1);
            }
        }
        const half8* wf = Wf + (size_t)s * 512 + g * 16 + c;   // + t*64 per col-tile
        #pragma unroll
        for (int t = 0; t < 8; ++t) {
            half8 bf = wf[t * 64];
            acc0[t] = __builtin_amdgcn_mfma_f32_16x16x32_f16(af0, bf, acc0[t], 0, 0, 0);
            acc1[t] = __builtin_amdgcn_mfma_f32_16x16x32_f16(af1, bf, acc1[t], 0, 0, 0);
        }
    }

    // ---- epilogue: +T, LayerNorm over 128 (16-lane shfl groups), store
    float ls[8], lo[8];
    #pragma unroll
    for (int t = 0; t < 8; ++t) {
        ls[t] = ln_scale[t * 16 + c];
        lo[t] = ln_offset[t * 16 + c];
    }
    #pragma unroll
    for (int a = 0; a < 2; ++a) {
        #pragma unroll
        for (int j = 0; j < 4; ++j) {
            int r = we0 + a * 16 + g * 4 + j;    // edge row for this C/D reg
            int m = m0 + r;
            int dI = sD[r];
            float v[8];
            float sum = 0.f;
            #pragma unroll
            for (int t = 0; t < 8; ++t) {
                float av = a ? acc1[t][j] : acc0[t][j];
                v[t] = av + Tt[dI * 128 + t * 16 + c];
                sum += v[t];
            }
            sum += __shfl_xor(sum, 1); sum += __shfl_xor(sum, 2);
            sum += __shfl_xor(sum, 4); sum += __shfl_xor(sum, 8);
            float mu = sum * (1.0f / 128.0f);
            float sq = 0.f;
            #pragma unroll
            for (int t = 0; t < 8; ++t) { v[t] -= mu; sq += v[t] * v[t]; }
            sq += __shfl_xor(sq, 1); sq += __shfl_xor(sq, 2);
            sq += __shfl_xor(sq, 4); sq += __shfl_xor(sq, 8);
            float rs = rsqrtf(sq * (1.0f / 128.0f) + 1e-5f);
            #pragma unroll
            for (int t = 0; t < 8; ++t)
                out[(size_t)m * 128 + t * 16 + c] = v[t] * rs * ls[t] + lo[t];
        }
    }
}

extern "C" void kernel_launch(void* const* d_in, const int* in_sizes, int n_in,
                              void* d_out, int out_size, void* d_ws, size_t ws_size,
                              hipStream_t stream) {
    const float* X           = (const float*)d_in[0];
    const float* mask        = (const float*)d_in[1];
    const int*   residue_idx = (const int*)d_in[2];
    const int*   chain_idx   = (const int*)d_in[3];
    const float* pe_w        = (const float*)d_in[4];
    const float* pe_b        = (const float*)d_in[5];
    const float* edge_w      = (const float*)d_in[6];
    const float* ln_scale    = (const float*)d_in[7];
    const float* ln_offset   = (const float*)d_in[8];

    float* out = (float*)d_out;

    // workspace layout (bytes)
    char* base = (char*)d_ws;
    float*     Y5   = (float*)(base);              // 8192*15*4 = 491520
    float*     Cx   = (float*)(base + 491520);     // 32768
    float*     Cy   = (float*)(base + 524288);     // 32768
    float*     Cz   = (float*)(base + 557056);     // 32768
    float*     Tt   = (float*)(base + 589824);     // 66*128*4  =  33792
    int*       eidx = (int*)  (base + 623616);     // 8192*30*4 = 983040
    _Float16*  Wf   = (_Float16*)(base + 1606656); // 13*8*4*16*8*2 = 106496

    float* E     = out;                 // 8192*30*128 floats
    float* eidxf = out + 31457280;      // 8192*30 floats (harness reads d_out as f32)

    prep_kernel<<<LRES / 256, 256, 0, stream>>>(X, Y5, Cx, Cy, Cz);
    pet_kernel<<<(66 * 128 + 255) / 256, 256, 0, stream>>>(pe_w, pe_b, edge_w, Tt);
    wcvt_kernel<<<(13 * 8 * 4 * 16 * 8 + 255) / 256, 256, 0, stream>>>(edge_w, Wf);
    topk_kernel<<<LRES, 512, 0, stream>>>(Cx, Cy, Cz, mask, eidx, eidxf);
    edge_kernel<<<(LRES * TOPK) / 128, 256, 0, stream>>>(Y5, Tt, (const half8*)Wf, eidx,
                                                         residue_idx, chain_idx,
                                                         ln_scale, ln_offset, E);
}